// Round 1
// 1452.615 us; speedup vs baseline: 1.1341x; 1.1341x over previous
//
#include <hip/hip_runtime.h>
#include <cstdint>
#include <cmath>

using u16 = unsigned short;

typedef __bf16 bf16x8 __attribute__((ext_vector_type(8)));
typedef float  f32x4  __attribute__((ext_vector_type(4)));

__device__ __forceinline__ float b2f(u16 u) {
    return __uint_as_float(((unsigned int)u) << 16);
}
__device__ __forceinline__ u16 f2b(float f) {
    unsigned int x = __float_as_uint(f);
    unsigned int r = (x + 0x7fffu + ((x >> 16) & 1u)) >> 16;
    return (u16)r;
}

// async global->LDS, 16B per lane; LDS dest is wave-uniform base + lane*16.
__device__ __forceinline__ void gload16(const u16* g, u16* l) {
    __builtin_amdgcn_global_load_lds((__attribute__((address_space(1))) void*)g,
                                     (__attribute__((address_space(3))) void*)l,
                                     16, 0, 0);
}

// ---------------------------------------------------------------------------
// Input dtype detection: f32 N(0,1) data has exponent field in ~[117,130];
// bf16 pairs read as f32 decode to exponents ~250+. Writes 1 if f32.
__global__ void detect_dtype(const unsigned int* __restrict__ x, int* __restrict__ flag) {
    __shared__ int cnt[256];
    int tid = threadIdx.x;
    int c = 0;
#pragma unroll
    for (int i = 0; i < 16; ++i) {
        unsigned int w = x[tid * 16 + i];
        int e = (w >> 23) & 0xFF;
        if (e >= 100 && e <= 150) ++c;
    }
    cnt[tid] = c;
    __syncthreads();
    if (tid == 0) {
        int s = 0;
        for (int i = 0; i < 256; ++i) s += cnt[i];
        flag[0] = (s > 3072) ? 1 : 0;
    }
}

// Convert any input tensor to canonical bf16 (copy if already bf16).
__global__ void convertk(const void* __restrict__ src, u16* __restrict__ dst, int n,
                         const int* __restrict__ flagp) {
    int isf = flagp[0];
    int i = blockIdx.x * 256 + threadIdx.x;
    if (i < n) dst[i] = isf ? f2b(((const float*)src)[i]) : ((const u16*)src)[i];
}

// ---------------------------------------------------------------------------
// Weight transpose: in (K,N) bf16 -> out (N,K).  grid (N/32, K/32), block 256.
__global__ void wtrans(const u16* __restrict__ in, u16* __restrict__ out, int K, int N) {
    __shared__ u16 tile[32][33];
    int n0 = blockIdx.x * 32, k0 = blockIdx.y * 32;
    int tx = threadIdx.x & 31, ty = threadIdx.x >> 5;  // 32 x 8
#pragma unroll
    for (int i = 0; i < 4; ++i)
        tile[ty + i * 8][tx] = in[(size_t)(k0 + ty + i * 8) * N + n0 + tx];
    __syncthreads();
#pragma unroll
    for (int i = 0; i < 4; ++i)
        out[(size_t)(n0 + ty + i * 8) * K + k0 + tx] = tile[tx][ty + i * 8];
}

// ---------------------------------------------------------------------------
// LN1 stats over C for x in (B,C,HW), dtype per flag. One thread per token.
__global__ void ln1_stats(const void* __restrict__ x, float* __restrict__ mean,
                          float* __restrict__ rstd, const int* __restrict__ flagp) {
    int isf = flagp[0];
    int t = blockIdx.x * 256 + threadIdx.x;      // < 100352
    int b = t / 12544, hw = t - b * 12544;
    size_t base = (size_t)b * 384 * 12544 + hw;
    float s = 0.f, sq = 0.f;
    if (isf) {
        const float* p = (const float*)x + base;
        for (int c = 0; c < 384; ++c) {
            float v = p[(size_t)c * 12544];
            s += v; sq += v * v;
        }
    } else {
        const u16* p = (const u16*)x + base;
        for (int c = 0; c < 384; ++c) {
            float v = b2f(p[(size_t)c * 12544]);
            s += v; sq += v * v;
        }
    }
    float m = s * (1.0f / 384.0f);
    float var = sq * (1.0f / 384.0f) - m * m;
    mean[t] = m;
    rstd[t] = rsqrtf(var + 1e-5f);
}

// Transpose + normalize: x(B,C,HW) -> xt(T,C) raw bf16, xn(T,C) normalized bf16.
// grid (HW/64=196, C/64=6, B=8), block 256.
__global__ void ln1_apply(const void* __restrict__ x, const float* __restrict__ mean,
                          const float* __restrict__ rstd, const u16* __restrict__ g1,
                          const u16* __restrict__ b1, u16* __restrict__ xt,
                          u16* __restrict__ xn, const int* __restrict__ flagp) {
    __shared__ float tile[64][65];
    int isf = flagp[0];
    int hw0 = blockIdx.x * 64, c0 = blockIdx.y * 64, b = blockIdx.z;
    int tid = threadIdx.x;
    {
        int hl = tid & 63, cq = tid >> 6;
        size_t base = ((size_t)b * 384 + c0) * 12544 + hw0;
#pragma unroll
        for (int it = 0; it < 16; ++it) {
            int cl = cq * 16 + it;
            size_t idx = base + (size_t)cl * 12544 + hl;
            tile[cl][hl] = isf ? ((const float*)x)[idx] : b2f(((const u16*)x)[idx]);
        }
    }
    __syncthreads();
    {
        int cl = tid & 63, hq = tid >> 6;
        float g = b2f(g1[c0 + cl]), bb = b2f(b1[c0 + cl]);
#pragma unroll
        for (int it = 0; it < 16; ++it) {
            int hl = hq * 16 + it;
            int t = b * 12544 + hw0 + hl;
            float v = tile[cl][hl];
            size_t o = (size_t)t * 384 + c0 + cl;
            xt[o] = f2b(v);
            xn[o] = f2b((v - mean[t]) * rstd[t] * g + bb);
        }
    }
}

// ---------------------------------------------------------------------------
// bf16 GEMM: C = A(MxK) * Bt(NxK)^T + bias, m97 structure:
// global_load_lds width-16 staging, 128x128 tile, BK=32, 2 barriers/K-step.
// XCD-aware bijective block swizzle. LDS-staged f32 epilogue for coalesced
// 16B stores (single rounding; residual read also coalesced).
// EPI 0: bias. 1: bias+gelu(exact). 2: bias+res add.
template <int EPI>
__global__ void gemm_bt(const u16* __restrict__ A, const u16* __restrict__ Bt,
                        const u16* __restrict__ bias, const u16* __restrict__ res,
                        u16* __restrict__ Cout, int M, int N, int K) {
    __shared__ __align__(16) u16 S[2][128 * 32];   // A-tile, B-tile (8KB each)
    const int tid = threadIdx.x;
    const int wave = tid >> 6, lane = tid & 63;

    // XCD-aware bijective swizzle of flattened block id (8 XCDs)
    const int nbx = gridDim.x;
    const int nwg = nbx * gridDim.y;
    int flat = blockIdx.y * nbx + blockIdx.x;
    {
        int q = nwg >> 3, r = nwg & 7;
        int xcd = flat & 7, loc = flat >> 3;
        flat = (xcd < r ? xcd * (q + 1) : r * (q + 1) + (xcd - r) * q) + loc;
    }
    const int m0 = (flat / nbx) * 128, n0 = (flat % nbx) * 128;

    const int wm = wave & 1, wn = wave >> 1;
    const int m15 = lane & 15, q4 = lane >> 4;

    // staging: each gload16 covers 16 rows x 32 cols (1KB), lane i ->
    // row (i>>2), col (i&3)*8 — linear in LDS, matching HW's base+lane*16B.
    const u16* gA = A + (size_t)(m0 + wave * 32 + (lane >> 2)) * K + (lane & 3) * 8;
    const u16* gB = Bt + (size_t)(n0 + wave * 32 + (lane >> 2)) * K + (lane & 3) * 8;
    u16* lA0 = &S[0][(wave * 32) * 32];
    u16* lA1 = &S[0][(wave * 32 + 16) * 32];
    u16* lB0 = &S[1][(wave * 32) * 32];
    u16* lB1 = &S[1][(wave * 32 + 16) * 32];

    f32x4 acc[4][4];
#pragma unroll
    for (int i = 0; i < 4; ++i)
#pragma unroll
        for (int j = 0; j < 4; ++j) acc[i][j] = {0.f, 0.f, 0.f, 0.f};

    for (int k0 = 0; k0 < K; k0 += 32) {
        __syncthreads();  // prev iteration's fragment reads complete (WAR)
        gload16(gA + k0, lA0);
        gload16(gA + k0 + 16 * K, lA1);
        gload16(gB + k0, lB0);
        gload16(gB + k0 + 16 * K, lB1);
        __syncthreads();  // compiler drains vmcnt(0) before s_barrier (RAW)
        bf16x8 af[4], bfr[4];
#pragma unroll
        for (int i = 0; i < 4; ++i)
            af[i] = *(const bf16x8*)&S[0][(wm * 64 + i * 16 + m15) * 32 + q4 * 8];
#pragma unroll
        for (int j = 0; j < 4; ++j)
            bfr[j] = *(const bf16x8*)&S[1][(wn * 64 + j * 16 + m15) * 32 + q4 * 8];
#pragma unroll
        for (int i = 0; i < 4; ++i)
#pragma unroll
            for (int j = 0; j < 4; ++j)
                acc[i][j] = __builtin_amdgcn_mfma_f32_16x16x32_bf16(af[i], bfr[j],
                                                                    acc[i][j], 0, 0, 0);
    }

    // Epilogue: 4 passes of 32 rows through a 32x128 f32 LDS tile (16KB).
    float* Cs = (float*)&S[0][0];
#pragma unroll
    for (int p = 0; p < 4; ++p) {
        __syncthreads();  // Cs free (main-loop reads / prev pass stores done)
        if (wm == (p >> 1)) {
            const int ibase = (p & 1) * 2;
#pragma unroll
            for (int jj = 0; jj < 4; ++jj) {
                int n = n0 + wn * 64 + jj * 16 + m15;
                float bv = b2f(bias[n]);
#pragma unroll
                for (int ii = 0; ii < 2; ++ii) {
                    int i = ibase + ii;
#pragma unroll
                    for (int r = 0; r < 4; ++r) {
                        float v = acc[i][jj][r] + bv;
                        if (EPI == 1) v = 0.5f * v * (1.0f + erff(v * 0.70710678118f));
                        Cs[(ii * 16 + q4 * 4 + r) * 128 + wn * 64 + jj * 16 + m15] = v;
                    }
                }
            }
        }
        __syncthreads();  // staged values visible
#pragma unroll
        for (int it = 0; it < 2; ++it) {
            int r2 = it * 16 + (tid >> 4);
            int c8 = (tid & 15) * 8;
            size_t goff = (size_t)(m0 + p * 32 + r2) * N + n0 + c8;
            const float* src = &Cs[r2 * 128 + c8];
            uint4 rv;
            const u16* rp = (const u16*)&rv;
            if (EPI == 2) rv = *(const uint4*)&res[goff];
            u16 outv[8];
#pragma unroll
            for (int e = 0; e < 8; ++e) {
                float v = src[e];
                if (EPI == 2) v += b2f(rp[e]);
                outv[e] = f2b(v);
            }
            *(uint4*)&Cout[goff] = *(const uint4*)outv;
        }
    }
}

// ---------------------------------------------------------------------------
// Window attention. One block per window (2048), 4 waves; wave w does heads
// w, w+4, w+8.
__global__ void attn_win(const u16* __restrict__ qkv, const u16* __restrict__ rpb,
                         u16* __restrict__ outp) {
    __shared__ __align__(16) u16 lds[4][6144];
    const int tid = threadIdx.x;
    const int wave = tid >> 6, lane = tid & 63;
    const int wid = blockIdx.x;
    const int b = wid >> 8, wy = (wid >> 4) & 15, wx = wid & 15;
    const int t0 = b * 12544 + wy * 7 * 112 + wx * 7;
    u16* Qs = &lds[wave][0];
    u16* Ks = &lds[wave][2048];
    u16* Vt = &lds[wave][4096];
    u16* Ps = Qs;  // alias: P written only after Q/K consumed into registers
    const int m15 = lane & 15, q4 = lane >> 4;
    const int rr = lane >> 2, dq = lane & 3;
    const float scale = 0.17677669529663687f;  // 1/sqrt(32)

    for (int hl = 0; hl < 3; ++hl) {
        const int h = hl * 4 + wave;
        __syncthreads();  // prior iteration's LDS reads done before overwrite
#pragma unroll
        for (int p = 0; p < 4; ++p) {
            int n = p * 16 + rr;
            uint4 qv = {0u, 0u, 0u, 0u}, kv = {0u, 0u, 0u, 0u}, vv = {0u, 0u, 0u, 0u};
            if (n < 49) {
                int t = t0 + (n / 7) * 112 + (n % 7);
                const u16* gq = qkv + (size_t)t * 1152 + h * 32 + dq * 8;
                qv = *(const uint4*)gq;
                kv = *(const uint4*)(gq + 384);
                vv = *(const uint4*)(gq + 768);
            }
            *(uint4*)&Qs[n * 32 + dq * 8] = qv;
            *(uint4*)&Ks[n * 32 + dq * 8] = kv;
            const u16* pv = (const u16*)&vv;
#pragma unroll
            for (int ii = 0; ii < 8; ++ii) Vt[(dq * 8 + ii) * 64 + n] = pv[ii];
        }
        __syncthreads();  // staging visible before fragment reads
        bf16x8 qf[4], kf[4];
#pragma unroll
        for (int i = 0; i < 4; ++i)
            qf[i] = *(const bf16x8*)&Qs[(i * 16 + m15) * 32 + q4 * 8];
#pragma unroll
        for (int j = 0; j < 4; ++j)
            kf[j] = *(const bf16x8*)&Ks[(j * 16 + m15) * 32 + q4 * 8];
        bf16x8 vf[2][2];
#pragma unroll
        for (int j = 0; j < 2; ++j)
#pragma unroll
            for (int kk = 0; kk < 2; ++kk)
                vf[j][kk] = *(const bf16x8*)&Vt[(j * 16 + m15) * 64 + kk * 32 + q4 * 8];
        f32x4 sc[4][4];
#pragma unroll
        for (int i = 0; i < 4; ++i)
#pragma unroll
            for (int j = 0; j < 4; ++j) {
                sc[i][j] = {0.f, 0.f, 0.f, 0.f};
                sc[i][j] = __builtin_amdgcn_mfma_f32_16x16x32_bf16(qf[i], kf[j],
                                                                   sc[i][j], 0, 0, 0);
            }
#pragma unroll
        for (int i = 0; i < 4; ++i) {
#pragma unroll
            for (int r = 0; r < 4; ++r) {
                int row = i * 16 + q4 * 4 + r;
                int rc = row < 49 ? row : 48;
                int ri = rc / 7, rj = rc - ri * 7;
#pragma unroll
                for (int j = 0; j < 4; ++j) {
                    int col = j * 16 + m15;
                    int cc = col < 49 ? col : 48;
                    int mi = cc / 7, mj = cc - mi * 7;
                    int idx = ((ri - mi + 6) * 13 + (rj - mj + 6)) * 12 + h;
                    float bias = b2f(rpb[idx]);
                    float s = sc[i][j][r] * scale + bias;
                    sc[i][j][r] = (row < 49 && col < 49) ? s : -1e30f;
                }
            }
        }
#pragma unroll
        for (int i = 0; i < 4; ++i) {
#pragma unroll
            for (int r = 0; r < 4; ++r) {
                float mx = fmaxf(fmaxf(sc[i][0][r], sc[i][1][r]),
                                 fmaxf(sc[i][2][r], sc[i][3][r]));
                mx = fmaxf(mx, __shfl_xor(mx, 1));
                mx = fmaxf(mx, __shfl_xor(mx, 2));
                mx = fmaxf(mx, __shfl_xor(mx, 4));
                mx = fmaxf(mx, __shfl_xor(mx, 8));
                float e0 = __expf(sc[i][0][r] - mx);
                float e1 = __expf(sc[i][1][r] - mx);
                float e2 = __expf(sc[i][2][r] - mx);
                float e3 = __expf(sc[i][3][r] - mx);
                float sum = e0 + e1 + e2 + e3;
                sum += __shfl_xor(sum, 1);
                sum += __shfl_xor(sum, 2);
                sum += __shfl_xor(sum, 4);
                sum += __shfl_xor(sum, 8);
                float inv = 1.0f / sum;
                sc[i][0][r] = e0 * inv;
                sc[i][1][r] = e1 * inv;
                sc[i][2][r] = e2 * inv;
                sc[i][3][r] = e3 * inv;
            }
        }
#pragma unroll
        for (int i = 0; i < 4; ++i)
#pragma unroll
            for (int r = 0; r < 4; ++r)
#pragma unroll
                for (int j = 0; j < 4; ++j)
                    Ps[(i * 16 + q4 * 4 + r) * 64 + j * 16 + m15] = f2b(sc[i][j][r]);
        __syncthreads();  // P stores visible before pf loads
        f32x4 oacc[4][2];
#pragma unroll
        for (int i = 0; i < 4; ++i)
#pragma unroll
            for (int j = 0; j < 2; ++j) oacc[i][j] = {0.f, 0.f, 0.f, 0.f};
#pragma unroll
        for (int i = 0; i < 4; ++i) {
#pragma unroll
            for (int kk = 0; kk < 2; ++kk) {
                bf16x8 pf = *(const bf16x8*)&Ps[(i * 16 + m15) * 64 + kk * 32 + q4 * 8];
#pragma unroll
                for (int j = 0; j < 2; ++j)
                    oacc[i][j] = __builtin_amdgcn_mfma_f32_16x16x32_bf16(pf, vf[j][kk],
                                                                         oacc[i][j], 0, 0, 0);
            }
        }
#pragma unroll
        for (int i = 0; i < 4; ++i) {
#pragma unroll
            for (int r = 0; r < 4; ++r) {
                int row = i * 16 + q4 * 4 + r;
                if (row < 49) {
                    int t = t0 + (row / 7) * 112 + (row % 7);
#pragma unroll
                    for (int j = 0; j < 2; ++j)
                        outp[(size_t)t * 384 + h * 32 + j * 16 + m15] = f2b(oacc[i][j][r]);
                }
            }
        }
    }
}

// ---------------------------------------------------------------------------
// LN2: y(T,384) bf16 -> out(T,384) bf16. One wave per token.
__global__ void ln2_kernel(const u16* __restrict__ y, const u16* __restrict__ g2,
                           const u16* __restrict__ b2, u16* __restrict__ out) {
    int wave = threadIdx.x >> 6, lane = threadIdx.x & 63;
    size_t t = (size_t)blockIdx.x * 4 + wave;
    const u16* row = y + t * 384;
    float v[6];
    float s = 0.f, sq = 0.f;
#pragma unroll
    for (int i = 0; i < 6; ++i) {
        v[i] = b2f(row[lane + i * 64]);
        s += v[i]; sq += v[i] * v[i];
    }
#pragma unroll
    for (int m = 1; m < 64; m <<= 1) {
        s += __shfl_xor(s, m);
        sq += __shfl_xor(sq, m);
    }
    float mean = s * (1.0f / 384.0f);
    float var = sq * (1.0f / 384.0f) - mean * mean;
    float rstd = rsqrtf(var + 1e-5f);
#pragma unroll
    for (int i = 0; i < 6; ++i) {
        int c = lane + i * 64;
        out[t * 384 + c] = f2b((v[i] - mean) * rstd * b2f(g2[c]) + b2f(b2[c]));
    }
}

// ---------------------------------------------------------------------------
// final (T,384) bf16 -> out (B,384,112,112), dtype per flag. grid (196,6,8).
__global__ void out_transpose(const u16* __restrict__ fin, void* __restrict__ out,
                              const int* __restrict__ flagp) {
    __shared__ float tile[64][65];
    int isf = flagp[0];
    int hw0 = blockIdx.x * 64, c0 = blockIdx.y * 64, b = blockIdx.z;
    int tid = threadIdx.x;
    {
        int cl = tid & 63, hq = tid >> 6;
#pragma unroll
        for (int it = 0; it < 16; ++it) {
            int hl = hq * 16 + it;
            int t = b * 12544 + hw0 + hl;
            tile[hl][cl] = b2f(fin[(size_t)t * 384 + c0 + cl]);
        }
    }
    __syncthreads();
    {
        int hl = tid & 63, cq = tid >> 6;
#pragma unroll
        for (int it = 0; it < 16; ++it) {
            int cl = cq * 16 + it;
            size_t o = ((size_t)b * 384 + c0 + cl) * 12544 + hw0 + hl;
            float v = tile[hl][cl];
            if (isf) ((float*)out)[o] = v;
            else     ((u16*)out)[o] = f2b(v);
        }
    }
}

// ---------------------------------------------------------------------------
extern "C" void kernel_launch(void* const* d_in, const int* in_sizes, int n_in,
                              void* d_out, int out_size, void* d_ws, size_t ws_size,
                              hipStream_t stream) {
    constexpr int T = 100352, C = 384, HID = 1536, NQ = 1152;
    const void* x      = d_in[0];
    u16* out_any = (u16*)d_out;  // dtype resolved device-side
    (void)out_any;

    char* ws = (char*)d_ws;
    size_t off = 0;
    auto alloc = [&](size_t bytes) { char* p = ws + off; off += (bytes + 255) & ~(size_t)255; return p; };
    int*   flag   = (int*)alloc(4);
    // canonical bf16 copies of all non-x inputs
    u16* cw_qkv  = (u16*)alloc((size_t)C * NQ * 2);
    u16* cb_qkv  = (u16*)alloc((size_t)NQ * 2);
    u16* crpb    = (u16*)alloc((size_t)169 * 12 * 2);
    u16* cw_proj = (u16*)alloc((size_t)C * C * 2);
    u16* cb_proj = (u16*)alloc((size_t)C * 2);
    u16* cg1     = (u16*)alloc((size_t)C * 2);
    u16* cb1     = (u16*)alloc((size_t)C * 2);
    u16* cg2     = (u16*)alloc((size_t)C * 2);
    u16* cb2     = (u16*)alloc((size_t)C * 2);
    u16* cw_fc1  = (u16*)alloc((size_t)C * HID * 2);
    u16* cb_fc1  = (u16*)alloc((size_t)HID * 2);
    u16* cw_fc2  = (u16*)alloc((size_t)HID * C * 2);
    u16* cb_fc2  = (u16*)alloc((size_t)C * 2);
    // transposed weights
    u16* wqkvT  = (u16*)alloc((size_t)C * NQ * 2);
    u16* wprojT = (u16*)alloc((size_t)C * C * 2);
    u16* wfc1T  = (u16*)alloc((size_t)C * HID * 2);
    u16* wfc2T  = (u16*)alloc((size_t)HID * C * 2);
    // activations
    u16*   xt     = (u16*)alloc((size_t)T * C * 2);
    u16*   bufB   = (u16*)alloc((size_t)T * C * 2);    // xn -> attnout -> h_in -> final
    u16*   bufC   = (u16*)alloc((size_t)T * HID * 2);  // qkv -> hid
    u16*   ybuf   = (u16*)alloc((size_t)T * C * 2);
    float* meanb  = (float*)alloc((size_t)T * 4);
    float* rstdb  = (float*)alloc((size_t)T * 4);

    // 1) detect input dtype from x
    detect_dtype<<<1, 256, 0, stream>>>((const unsigned int*)x, flag);

    // 2) canonicalize all non-x inputs to bf16
    auto conv = [&](const void* src, u16* dst, int n) {
        convertk<<<(n + 255) / 256, 256, 0, stream>>>(src, dst, n, flag);
    };
    conv(d_in[1], cg1, C);
    conv(d_in[2], cb1, C);
    conv(d_in[3], cw_qkv, C * NQ);
    conv(d_in[4], cb_qkv, NQ);
    conv(d_in[5], crpb, 169 * 12);
    conv(d_in[6], cw_proj, C * C);
    conv(d_in[7], cb_proj, C);
    conv(d_in[8], cg2, C);
    conv(d_in[9], cb2, C);
    conv(d_in[10], cw_fc1, C * HID);
    conv(d_in[11], cb_fc1, HID);
    conv(d_in[12], cw_fc2, HID * C);
    conv(d_in[13], cb_fc2, C);

    // 3) weight transposes (B^T layout for GEMM)
    wtrans<<<dim3(NQ / 32, C / 32), 256, 0, stream>>>(cw_qkv, wqkvT, C, NQ);
    wtrans<<<dim3(C / 32, C / 32), 256, 0, stream>>>(cw_proj, wprojT, C, C);
    wtrans<<<dim3(HID / 32, C / 32), 256, 0, stream>>>(cw_fc1, wfc1T, C, HID);
    wtrans<<<dim3(C / 32, HID / 32), 256, 0, stream>>>(cw_fc2, wfc2T, HID, C);

    // 4) LN1 + transpose
    ln1_stats<<<T / 256, 256, 0, stream>>>(x, meanb, rstdb, flag);
    ln1_apply<<<dim3(196, 6, 8), 256, 0, stream>>>(x, meanb, rstdb, cg1, cb1, xt, bufB, flag);

    // 5) QKV
    gemm_bt<0><<<dim3(NQ / 128, T / 128), 256, 0, stream>>>(bufB, wqkvT, cb_qkv, nullptr,
                                                            bufC, T, NQ, C);
    // 6) attention (qkv in bufC -> attnout in bufB)
    attn_win<<<2048, 256, 0, stream>>>(bufC, crpb, bufB);

    // 7) proj + residual(xt) -> y
    gemm_bt<2><<<dim3(C / 128, T / 128), 256, 0, stream>>>(bufB, wprojT, cb_proj, xt,
                                                           ybuf, T, C, C);
    // 8) LN2 -> bufB
    ln2_kernel<<<T / 4, 256, 0, stream>>>(ybuf, cg2, cb2, bufB);

    // 9) FC1 + gelu -> hid (bufC)
    gemm_bt<1><<<dim3(HID / 128, T / 128), 256, 0, stream>>>(bufB, wfc1T, cb_fc1, nullptr,
                                                             bufC, T, HID, C);
    // 10) FC2 + residual(y) -> final (bufB)
    gemm_bt<2><<<dim3(C / 128, T / 128), 256, 0, stream>>>(bufC, wfc2T, cb_fc2, ybuf,
                                                           bufB, T, C, HID);
    // 11) final transpose to NCHW (dtype per flag)
    out_transpose<<<dim3(196, 6, 8), 256, 0, stream>>>(bufB, d_out, flag);
}

// Round 2
// 1334.902 us; speedup vs baseline: 1.2341x; 1.0882x over previous
//
#include <hip/hip_runtime.h>
#include <cstdint>
#include <cmath>

using u16 = unsigned short;

typedef __bf16 bf16x8 __attribute__((ext_vector_type(8)));
typedef float  f32x4  __attribute__((ext_vector_type(4)));

__device__ __forceinline__ float b2f(u16 u) {
    return __uint_as_float(((unsigned int)u) << 16);
}
__device__ __forceinline__ u16 f2b(float f) {
    unsigned int x = __float_as_uint(f);
    unsigned int r = (x + 0x7fffu + ((x >> 16) & 1u)) >> 16;
    return (u16)r;
}

// async global->LDS, 16B per lane; LDS dest is wave-uniform base + lane*16.
__device__ __forceinline__ void gload16(const u16* g, u16* l) {
    __builtin_amdgcn_global_load_lds((__attribute__((address_space(1))) void*)g,
                                     (__attribute__((address_space(3))) void*)l,
                                     16, 0, 0);
}

// exact-enough gelu: erf via Abramowitz-Stegun 7.1.26 (|err| <= 1.5e-7).
__device__ __forceinline__ float gelu_f(float x) {
    float z = fabsf(x) * 0.70710678118f;
    float t = __builtin_amdgcn_rcpf(fmaf(0.3275911f, z, 1.0f));
    float poly = fmaf(fmaf(fmaf(fmaf(1.061405429f, t, -1.453152027f),
                               t, 1.421413741f),
                          t, -0.284496736f),
                     t, 0.254829592f) * t;
    float e = __expf(-z * z);
    float erfv = copysignf(1.0f - poly * e, x);
    return 0.5f * x * (1.0f + erfv);
}

// token permutation: original (b, hw) -> window-gathered index t'
__device__ __forceinline__ int tprime(int b, int hw) {
    int r = hw / 112, c = hw - r * 112;
    int wy = r / 7, iy = r - wy * 7;
    int wx = c / 7, ix = c - wx * 7;
    return (b * 256 + wy * 16 + wx) * 49 + iy * 7 + ix;
}

// ---------------------------------------------------------------------------
// Input dtype detection: f32 N(0,1) data has exponent field in ~[117,130];
// bf16 pairs read as f32 decode to exponents ~250+. Writes 1 if f32.
__global__ void detect_dtype(const unsigned int* __restrict__ x, int* __restrict__ flag) {
    __shared__ int cnt[256];
    int tid = threadIdx.x;
    int c = 0;
#pragma unroll
    for (int i = 0; i < 16; ++i) {
        unsigned int w = x[tid * 16 + i];
        int e = (w >> 23) & 0xFF;
        if (e >= 100 && e <= 150) ++c;
    }
    cnt[tid] = c;
    __syncthreads();
    if (tid == 0) {
        int s = 0;
        for (int i = 0; i < 256; ++i) s += cnt[i];
        flag[0] = (s > 3072) ? 1 : 0;
    }
}

// Convert any input tensor to canonical bf16 (copy if already bf16).
__global__ void convertk(const void* __restrict__ src, u16* __restrict__ dst, int n,
                         const int* __restrict__ flagp) {
    int isf = flagp[0];
    int i = blockIdx.x * 256 + threadIdx.x;
    if (i < n) dst[i] = isf ? f2b(((const float*)src)[i]) : ((const u16*)src)[i];
}

// ---------------------------------------------------------------------------
// Weight transpose: in (K,N) bf16 -> out (N,K).  grid (N/32, K/32), block 256.
__global__ void wtrans(const u16* __restrict__ in, u16* __restrict__ out, int K, int N) {
    __shared__ u16 tile[32][33];
    int n0 = blockIdx.x * 32, k0 = blockIdx.y * 32;
    int tx = threadIdx.x & 31, ty = threadIdx.x >> 5;  // 32 x 8
#pragma unroll
    for (int i = 0; i < 4; ++i)
        tile[ty + i * 8][tx] = in[(size_t)(k0 + ty + i * 8) * N + n0 + tx];
    __syncthreads();
#pragma unroll
    for (int i = 0; i < 4; ++i)
        out[(size_t)(n0 + ty + i * 8) * K + k0 + tx] = tile[tx][ty + i * 8];
}

// ---------------------------------------------------------------------------
// LN1 stats over C for x in (B,C,HW), dtype per flag. One thread per token.
__global__ void ln1_stats(const void* __restrict__ x, float* __restrict__ mean,
                          float* __restrict__ rstd, const int* __restrict__ flagp) {
    int isf = flagp[0];
    int t = blockIdx.x * 256 + threadIdx.x;      // < 100352
    int b = t / 12544, hw = t - b * 12544;
    size_t base = (size_t)b * 384 * 12544 + hw;
    float s = 0.f, sq = 0.f;
    if (isf) {
        const float* p = (const float*)x + base;
        for (int c = 0; c < 384; ++c) {
            float v = p[(size_t)c * 12544];
            s += v; sq += v * v;
        }
    } else {
        const u16* p = (const u16*)x + base;
        for (int c = 0; c < 384; ++c) {
            float v = b2f(p[(size_t)c * 12544]);
            s += v; sq += v * v;
        }
    }
    float m = s * (1.0f / 384.0f);
    float var = sq * (1.0f / 384.0f) - m * m;
    mean[t] = m;
    rstd[t] = rsqrtf(var + 1e-5f);
}

// Transpose + normalize: x(B,C,HW) -> xt(T',C) raw bf16, xn(T',C) normalized
// bf16 — rows written in window-gathered t' order.
// grid (HW/64=196, C/64=6, B=8), block 256.
__global__ void ln1_apply(const void* __restrict__ x, const float* __restrict__ mean,
                          const float* __restrict__ rstd, const u16* __restrict__ g1,
                          const u16* __restrict__ b1, u16* __restrict__ xt,
                          u16* __restrict__ xn, const int* __restrict__ flagp) {
    __shared__ float tile[64][65];
    int isf = flagp[0];
    int hw0 = blockIdx.x * 64, c0 = blockIdx.y * 64, b = blockIdx.z;
    int tid = threadIdx.x;
    {
        int hl = tid & 63, cq = tid >> 6;
        size_t base = ((size_t)b * 384 + c0) * 12544 + hw0;
#pragma unroll
        for (int it = 0; it < 16; ++it) {
            int cl = cq * 16 + it;
            size_t idx = base + (size_t)cl * 12544 + hl;
            tile[cl][hl] = isf ? ((const float*)x)[idx] : b2f(((const u16*)x)[idx]);
        }
    }
    __syncthreads();
    {
        int cl = tid & 63, hq = tid >> 6;
        float g = b2f(g1[c0 + cl]), bb = b2f(b1[c0 + cl]);
#pragma unroll
        for (int it = 0; it < 16; ++it) {
            int hl = hq * 16 + it;
            int hw = hw0 + hl;
            int t = b * 12544 + hw;                 // original order (stats)
            int tp = tprime(b, hw);                 // window-gathered order
            float v = tile[cl][hl];
            size_t o = (size_t)tp * 384 + c0 + cl;
            xt[o] = f2b(v);
            xn[o] = f2b((v - mean[t]) * rstd[t] * g + bb);
        }
    }
}

// ---------------------------------------------------------------------------
// bf16 GEMM: C = A(MxK) * Bt(NxK)^T + bias.
// Double-buffered global_load_lds staging, ONE barrier per K-step (loads for
// step t+1 overlap MFMA of step t). 128x128 tile, BK=32. XCD-aware bijective
// block swizzle. Conflict-free LDS-staged f32 epilogue (stride 132) with
// coalesced 16B stores. EPI 0: bias. 1: bias+gelu. 2: bias+res add.
template <int EPI>
__global__ void gemm_bt(const u16* __restrict__ A, const u16* __restrict__ Bt,
                        const u16* __restrict__ bias, const u16* __restrict__ res,
                        u16* __restrict__ Cout, int M, int N, int K) {
    __shared__ __align__(16) u16 S[2][2][128 * 32];   // [buf][A/B], 32 KB total
    const int tid = threadIdx.x;
    const int wave = tid >> 6, lane = tid & 63;

    // XCD-aware bijective swizzle of flattened block id (8 XCDs)
    const int nbx = gridDim.x;
    const int nwg = nbx * gridDim.y;
    int flat = blockIdx.y * nbx + blockIdx.x;
    {
        int q = nwg >> 3, r = nwg & 7;
        int xcd = flat & 7, loc = flat >> 3;
        flat = (xcd < r ? xcd * (q + 1) : r * (q + 1) + (xcd - r) * q) + loc;
    }
    const int m0 = (flat / nbx) * 128, n0 = (flat % nbx) * 128;

    const int wm = wave & 1, wn = wave >> 1;
    const int m15 = lane & 15, q4 = lane >> 4;

    // staging: lane i -> row (i>>2), col (i&3)*8 — linear base+lane*16B in LDS.
    const u16* gA = A + (size_t)(m0 + wave * 32 + (lane >> 2)) * K + (lane & 3) * 8;
    const u16* gB = Bt + (size_t)(n0 + wave * 32 + (lane >> 2)) * K + (lane & 3) * 8;

    f32x4 acc[4][4];
#pragma unroll
    for (int i = 0; i < 4; ++i)
#pragma unroll
        for (int j = 0; j < 4; ++j) acc[i][j] = {0.f, 0.f, 0.f, 0.f};

    const int nt = K >> 5;
    // prologue: stage tile 0 into buffer 0
    {
        u16* lA = &S[0][0][(wave * 32) * 32];
        u16* lB = &S[0][1][(wave * 32) * 32];
        gload16(gA, lA);
        gload16(gA + 16 * (size_t)K, lA + 16 * 32);
        gload16(gB, lB);
        gload16(gB + 16 * (size_t)K, lB + 16 * 32);
    }
    __syncthreads();   // drains vmcnt(0): tile 0 visible

    for (int t = 0; t < nt; ++t) {
        const int cur = t & 1;
        if (t + 1 < nt) {   // stage next tile into other buffer (overlaps MFMA)
            const int k0 = (t + 1) << 5;
            u16* lA = &S[cur ^ 1][0][(wave * 32) * 32];
            u16* lB = &S[cur ^ 1][1][(wave * 32) * 32];
            gload16(gA + k0, lA);
            gload16(gA + k0 + 16 * (size_t)K, lA + 16 * 32);
            gload16(gB + k0, lB);
            gload16(gB + k0 + 16 * (size_t)K, lB + 16 * 32);
        }
        bf16x8 af[4], bfr[4];
#pragma unroll
        for (int i = 0; i < 4; ++i)
            af[i] = *(const bf16x8*)&S[cur][0][(wm * 64 + i * 16 + m15) * 32 + q4 * 8];
#pragma unroll
        for (int j = 0; j < 4; ++j)
            bfr[j] = *(const bf16x8*)&S[cur][1][(wn * 64 + j * 16 + m15) * 32 + q4 * 8];
#pragma unroll
        for (int i = 0; i < 4; ++i)
#pragma unroll
            for (int j = 0; j < 4; ++j)
                acc[i][j] = __builtin_amdgcn_mfma_f32_16x16x32_bf16(af[i], bfr[j],
                                                                    acc[i][j], 0, 0, 0);
        __syncthreads();  // drains next-tile loads; guards WAR for buffer reuse
    }

    // Epilogue: 4 passes of 32 rows through a 32x132-stride f32 LDS tile.
    constexpr int CSTR = 132;   // +4 pad: bank shift 4/row -> conflict-free
    float* Cs = (float*)&S[0][0][0];   // 32*132*4 = 16.9 KB (fits in 32 KB)
#pragma unroll
    for (int p = 0; p < 4; ++p) {
        __syncthreads();  // Cs free (main-loop reads / prev pass reads done)
        if (wm == (p >> 1)) {
            const int ibase = (p & 1) * 2;
#pragma unroll
            for (int jj = 0; jj < 4; ++jj) {
                int n = n0 + wn * 64 + jj * 16 + m15;
                float bv = b2f(bias[n]);
#pragma unroll
                for (int ii = 0; ii < 2; ++ii) {
                    int i = ibase + ii;
#pragma unroll
                    for (int r = 0; r < 4; ++r) {
                        float v = acc[i][jj][r] + bv;
                        if (EPI == 1) v = gelu_f(v);
                        Cs[(ii * 16 + q4 * 4 + r) * CSTR + wn * 64 + jj * 16 + m15] = v;
                    }
                }
            }
        }
        __syncthreads();  // staged values visible
#pragma unroll
        for (int it = 0; it < 2; ++it) {
            int r2 = it * 16 + (tid >> 4);
            int c8 = (tid & 15) * 8;
            size_t goff = (size_t)(m0 + p * 32 + r2) * N + n0 + c8;
            f32x4 v0 = *(const f32x4*)&Cs[r2 * CSTR + c8];
            f32x4 v1 = *(const f32x4*)&Cs[r2 * CSTR + c8 + 4];
            uint4 rv = {0u, 0u, 0u, 0u};
            const u16* rp = (const u16*)&rv;
            if (EPI == 2) rv = *(const uint4*)&res[goff];
            u16 outv[8];
#pragma unroll
            for (int e = 0; e < 4; ++e) {
                float a = v0[e];
                if (EPI == 2) a += b2f(rp[e]);
                outv[e] = f2b(a);
                float bq = v1[e];
                if (EPI == 2) bq += b2f(rp[4 + e]);
                outv[4 + e] = f2b(bq);
            }
            *(uint4*)&Cout[goff] = *(const uint4*)outv;
        }
    }
}

// ---------------------------------------------------------------------------
// Window attention, window-gathered token order: window wid owns rows
// [wid*49, wid*49+49) of qkv/out — all reads/writes dense. One block per
// window (2048), 4 waves; wave w does heads w, w+4, w+8.
__global__ void attn_win(const u16* __restrict__ qkv, const u16* __restrict__ rpb,
                         u16* __restrict__ outp) {
    __shared__ __align__(16) u16 lds[4][6144];
    const int tid = threadIdx.x;
    const int wave = tid >> 6, lane = tid & 63;
    const int t0p = blockIdx.x * 49;
    u16* Qs = &lds[wave][0];
    u16* Ks = &lds[wave][2048];
    u16* Vt = &lds[wave][4096];
    u16* Ps = Qs;  // alias: P written only after Q/K consumed into registers
    const int m15 = lane & 15, q4 = lane >> 4;
    const int rr = lane >> 2, dq = lane & 3;
    const float scale = 0.17677669529663687f;  // 1/sqrt(32)

    for (int hl = 0; hl < 3; ++hl) {
        const int h = hl * 4 + wave;
        __syncthreads();  // prior iteration's LDS reads done before overwrite
#pragma unroll
        for (int p = 0; p < 4; ++p) {
            int n = p * 16 + rr;
            int nc = n < 49 ? n : 48;   // clamp: rows 49..63 masked later
            const u16* gq = qkv + (size_t)(t0p + nc) * 1152 + h * 32 + dq * 8;
            gload16(gq, &Qs[p * 512]);         // Q rows -> LDS (lane-linear)
            gload16(gq + 384, &Ks[p * 512]);   // K rows -> LDS
            uint4 vv = {0u, 0u, 0u, 0u};
            if (n < 49) vv = *(const uint4*)(gq + 768);
            const u16* pv = (const u16*)&vv;
#pragma unroll
            for (int ii = 0; ii < 8; ++ii) Vt[(dq * 8 + ii) * 64 + n] = pv[ii];
        }
        __syncthreads();  // staging (DMA + ds_write) visible before reads
        bf16x8 qf[4], kf[4];
#pragma unroll
        for (int i = 0; i < 4; ++i)
            qf[i] = *(const bf16x8*)&Qs[(i * 16 + m15) * 32 + q4 * 8];
#pragma unroll
        for (int j = 0; j < 4; ++j)
            kf[j] = *(const bf16x8*)&Ks[(j * 16 + m15) * 32 + q4 * 8];
        bf16x8 vf[2][2];
#pragma unroll
        for (int j = 0; j < 2; ++j)
#pragma unroll
            for (int kk = 0; kk < 2; ++kk)
                vf[j][kk] = *(const bf16x8*)&Vt[(j * 16 + m15) * 64 + kk * 32 + q4 * 8];
        f32x4 sc[4][4];
#pragma unroll
        for (int i = 0; i < 4; ++i)
#pragma unroll
            for (int j = 0; j < 4; ++j) {
                sc[i][j] = {0.f, 0.f, 0.f, 0.f};
                sc[i][j] = __builtin_amdgcn_mfma_f32_16x16x32_bf16(qf[i], kf[j],
                                                                   sc[i][j], 0, 0, 0);
            }
#pragma unroll
        for (int i = 0; i < 4; ++i) {
#pragma unroll
            for (int r = 0; r < 4; ++r) {
                int row = i * 16 + q4 * 4 + r;
                int rc = row < 49 ? row : 48;
                int ri = rc / 7, rj = rc - ri * 7;
#pragma unroll
                for (int j = 0; j < 4; ++j) {
                    int col = j * 16 + m15;
                    int cc = col < 49 ? col : 48;
                    int mi = cc / 7, mj = cc - mi * 7;
                    int idx = ((ri - mi + 6) * 13 + (rj - mj + 6)) * 12 + h;
                    float bias = b2f(rpb[idx]);
                    float s = sc[i][j][r] * scale + bias;
                    sc[i][j][r] = (row < 49 && col < 49) ? s : -1e30f;
                }
            }
        }
#pragma unroll
        for (int i = 0; i < 4; ++i) {
#pragma unroll
            for (int r = 0; r < 4; ++r) {
                float mx = fmaxf(fmaxf(sc[i][0][r], sc[i][1][r]),
                                 fmaxf(sc[i][2][r], sc[i][3][r]));
                mx = fmaxf(mx, __shfl_xor(mx, 1));
                mx = fmaxf(mx, __shfl_xor(mx, 2));
                mx = fmaxf(mx, __shfl_xor(mx, 4));
                mx = fmaxf(mx, __shfl_xor(mx, 8));
                float e0 = __expf(sc[i][0][r] - mx);
                float e1 = __expf(sc[i][1][r] - mx);
                float e2 = __expf(sc[i][2][r] - mx);
                float e3 = __expf(sc[i][3][r] - mx);
                float sum = e0 + e1 + e2 + e3;
                sum += __shfl_xor(sum, 1);
                sum += __shfl_xor(sum, 2);
                sum += __shfl_xor(sum, 4);
                sum += __shfl_xor(sum, 8);
                float inv = 1.0f / sum;
                sc[i][0][r] = e0 * inv;
                sc[i][1][r] = e1 * inv;
                sc[i][2][r] = e2 * inv;
                sc[i][3][r] = e3 * inv;
            }
        }
#pragma unroll
        for (int i = 0; i < 4; ++i)
#pragma unroll
            for (int r = 0; r < 4; ++r)
#pragma unroll
                for (int j = 0; j < 4; ++j)
                    Ps[(i * 16 + q4 * 4 + r) * 64 + j * 16 + m15] = f2b(sc[i][j][r]);
        __syncthreads();  // P stores visible before pf loads
        f32x4 oacc[4][2];
#pragma unroll
        for (int i = 0; i < 4; ++i)
#pragma unroll
            for (int j = 0; j < 2; ++j) oacc[i][j] = {0.f, 0.f, 0.f, 0.f};
#pragma unroll
        for (int i = 0; i < 4; ++i) {
#pragma unroll
            for (int kk = 0; kk < 2; ++kk) {
                bf16x8 pf = *(const bf16x8*)&Ps[(i * 16 + m15) * 64 + kk * 32 + q4 * 8];
#pragma unroll
                for (int j = 0; j < 2; ++j)
                    oacc[i][j] = __builtin_amdgcn_mfma_f32_16x16x32_bf16(pf, vf[j][kk],
                                                                         oacc[i][j], 0, 0, 0);
            }
        }
#pragma unroll
        for (int i = 0; i < 4; ++i) {
#pragma unroll
            for (int r = 0; r < 4; ++r) {
                int row = i * 16 + q4 * 4 + r;
                if (row < 49) {
#pragma unroll
                    for (int j = 0; j < 2; ++j)
                        outp[(size_t)(t0p + row) * 384 + h * 32 + j * 16 + m15] =
                            f2b(oacc[i][j][r]);
                }
            }
        }
    }
}

// ---------------------------------------------------------------------------
// LN2: y(T,384) bf16 -> out(T,384) bf16. One wave per token.
__global__ void ln2_kernel(const u16* __restrict__ y, const u16* __restrict__ g2,
                           const u16* __restrict__ b2, u16* __restrict__ out) {
    int wave = threadIdx.x >> 6, lane = threadIdx.x & 63;
    size_t t = (size_t)blockIdx.x * 4 + wave;
    const u16* row = y + t * 384;
    float v[6];
    float s = 0.f, sq = 0.f;
#pragma unroll
    for (int i = 0; i < 6; ++i) {
        v[i] = b2f(row[lane + i * 64]);
        s += v[i]; sq += v[i] * v[i];
    }
#pragma unroll
    for (int m = 1; m < 64; m <<= 1) {
        s += __shfl_xor(s, m);
        sq += __shfl_xor(sq, m);
    }
    float mean = s * (1.0f / 384.0f);
    float var = sq * (1.0f / 384.0f) - mean * mean;
    float rstd = rsqrtf(var + 1e-5f);
#pragma unroll
    for (int i = 0; i < 6; ++i) {
        int c = lane + i * 64;
        out[t * 384 + c] = f2b((v[i] - mean) * rstd * b2f(g2[c]) + b2f(b2[c]));
    }
}

// ---------------------------------------------------------------------------
// final (T',384) bf16 (window-gathered rows) -> out (B,384,112,112).
// grid (196,6,8), block 256.
__global__ void out_transpose(const u16* __restrict__ fin, void* __restrict__ out,
                              const int* __restrict__ flagp) {
    __shared__ float tile[64][65];
    int isf = flagp[0];
    int hw0 = blockIdx.x * 64, c0 = blockIdx.y * 64, b = blockIdx.z;
    int tid = threadIdx.x;
    {
        int cl = tid & 63, hq = tid >> 6;
#pragma unroll
        for (int it = 0; it < 16; ++it) {
            int hl = hq * 16 + it;
            int tp = tprime(b, hw0 + hl);
            tile[hl][cl] = b2f(fin[(size_t)tp * 384 + c0 + cl]);
        }
    }
    __syncthreads();
    {
        int hl = tid & 63, cq = tid >> 6;
#pragma unroll
        for (int it = 0; it < 16; ++it) {
            int cl = cq * 16 + it;
            size_t o = ((size_t)b * 384 + c0 + cl) * 12544 + hw0 + hl;
            float v = tile[hl][cl];
            if (isf) ((float*)out)[o] = v;
            else     ((u16*)out)[o] = f2b(v);
        }
    }
}

// ---------------------------------------------------------------------------
extern "C" void kernel_launch(void* const* d_in, const int* in_sizes, int n_in,
                              void* d_out, int out_size, void* d_ws, size_t ws_size,
                              hipStream_t stream) {
    constexpr int T = 100352, C = 384, HID = 1536, NQ = 1152;
    const void* x      = d_in[0];
    u16* out_any = (u16*)d_out;  // dtype resolved device-side
    (void)out_any;

    char* ws = (char*)d_ws;
    size_t off = 0;
    auto alloc = [&](size_t bytes) { char* p = ws + off; off += (bytes + 255) & ~(size_t)255; return p; };
    int*   flag   = (int*)alloc(4);
    // canonical bf16 copies of all non-x inputs
    u16* cw_qkv  = (u16*)alloc((size_t)C * NQ * 2);
    u16* cb_qkv  = (u16*)alloc((size_t)NQ * 2);
    u16* crpb    = (u16*)alloc((size_t)169 * 12 * 2);
    u16* cw_proj = (u16*)alloc((size_t)C * C * 2);
    u16* cb_proj = (u16*)alloc((size_t)C * 2);
    u16* cg1     = (u16*)alloc((size_t)C * 2);
    u16* cb1     = (u16*)alloc((size_t)C * 2);
    u16* cg2     = (u16*)alloc((size_t)C * 2);
    u16* cb2     = (u16*)alloc((size_t)C * 2);
    u16* cw_fc1  = (u16*)alloc((size_t)C * HID * 2);
    u16* cb_fc1  = (u16*)alloc((size_t)HID * 2);
    u16* cw_fc2  = (u16*)alloc((size_t)HID * C * 2);
    u16* cb_fc2  = (u16*)alloc((size_t)C * 2);
    // transposed weights
    u16* wqkvT  = (u16*)alloc((size_t)C * NQ * 2);
    u16* wprojT = (u16*)alloc((size_t)C * C * 2);
    u16* wfc1T  = (u16*)alloc((size_t)C * HID * 2);
    u16* wfc2T  = (u16*)alloc((size_t)HID * C * 2);
    // activations (all token-major buffers in window-gathered t' order)
    u16*   xt     = (u16*)alloc((size_t)T * C * 2);
    u16*   bufB   = (u16*)alloc((size_t)T * C * 2);    // xn -> attnout -> h_in -> final
    u16*   bufC   = (u16*)alloc((size_t)T * HID * 2);  // qkv -> hid
    u16*   ybuf   = (u16*)alloc((size_t)T * C * 2);
    float* meanb  = (float*)alloc((size_t)T * 4);
    float* rstdb  = (float*)alloc((size_t)T * 4);

    // 1) detect input dtype from x
    detect_dtype<<<1, 256, 0, stream>>>((const unsigned int*)x, flag);

    // 2) canonicalize all non-x inputs to bf16
    auto conv = [&](const void* src, u16* dst, int n) {
        convertk<<<(n + 255) / 256, 256, 0, stream>>>(src, dst, n, flag);
    };
    conv(d_in[1], cg1, C);
    conv(d_in[2], cb1, C);
    conv(d_in[3], cw_qkv, C * NQ);
    conv(d_in[4], cb_qkv, NQ);
    conv(d_in[5], crpb, 169 * 12);
    conv(d_in[6], cw_proj, C * C);
    conv(d_in[7], cb_proj, C);
    conv(d_in[8], cg2, C);
    conv(d_in[9], cb2, C);
    conv(d_in[10], cw_fc1, C * HID);
    conv(d_in[11], cb_fc1, HID);
    conv(d_in[12], cw_fc2, HID * C);
    conv(d_in[13], cb_fc2, C);

    // 3) weight transposes (B^T layout for GEMM)
    wtrans<<<dim3(NQ / 32, C / 32), 256, 0, stream>>>(cw_qkv, wqkvT, C, NQ);
    wtrans<<<dim3(C / 32, C / 32), 256, 0, stream>>>(cw_proj, wprojT, C, C);
    wtrans<<<dim3(HID / 32, C / 32), 256, 0, stream>>>(cw_fc1, wfc1T, C, HID);
    wtrans<<<dim3(C / 32, HID / 32), 256, 0, stream>>>(cw_fc2, wfc2T, HID, C);

    // 4) LN1 + transpose (outputs in window-gathered t' order)
    ln1_stats<<<T / 256, 256, 0, stream>>>(x, meanb, rstdb, flag);
    ln1_apply<<<dim3(196, 6, 8), 256, 0, stream>>>(x, meanb, rstdb, cg1, cb1, xt, bufB, flag);

    // 5) QKV
    gemm_bt<0><<<dim3(NQ / 128, T / 128), 256, 0, stream>>>(bufB, wqkvT, cb_qkv, nullptr,
                                                            bufC, T, NQ, C);
    // 6) attention (qkv in bufC -> attnout in bufB), dense per-window rows
    attn_win<<<2048, 256, 0, stream>>>(bufC, crpb, bufB);

    // 7) proj + residual(xt) -> y
    gemm_bt<2><<<dim3(C / 128, T / 128), 256, 0, stream>>>(bufB, wprojT, cb_proj, xt,
                                                           ybuf, T, C, C);
    // 8) LN2 -> bufB
    ln2_kernel<<<T / 4, 256, 0, stream>>>(ybuf, cg2, cb2, bufB);

    // 9) FC1 + gelu -> hid (bufC)
    gemm_bt<1><<<dim3(HID / 128, T / 128), 256, 0, stream>>>(bufB, wfc1T, cb_fc1, nullptr,
                                                             bufC, T, HID, C);
    // 10) FC2 + residual(y) -> final (bufB)
    gemm_bt<2><<<dim3(C / 128, T / 128), 256, 0, stream>>>(bufC, wfc2T, cb_fc2, ybuf,
                                                           bufB, T, C, HID);
    // 11) final transpose to NCHW (dtype per flag)
    out_transpose<<<dim3(196, 6, 8), 256, 0, stream>>>(bufB, d_out, flag);
}